// Round 2
// baseline (209.899 us; speedup 1.0000x reference)
//
#include <hip/hip_runtime.h>
#include <hip/hip_bf16.h>

#define BB 4
#define CC 64
#define HH 192
#define WW 192
#define HWSZ (HH*WW)          // 36864
#define HD 96
#define WD 96
#define GG 32
// fused kernel geometry: 512 threads, 128 pixels (4 threads/pixel in phase 1)
#define FTH 512
#define FPX 128
#define FBPB (HWSZ/FPX)       // 288 blocks per batch; grid 1152

typedef short short8 __attribute__((ext_vector_type(8)));
typedef float f32x4  __attribute__((ext_vector_type(4)));

__device__ __forceinline__ unsigned short f2bf(float f) {
    unsigned u = __float_as_uint(f);
    return (unsigned short)((u + 0x7FFFu + ((u >> 16) & 1u)) >> 16);
}
__device__ __forceinline__ float bf2f(unsigned short s) {
    return __uint_as_float(((unsigned)s) << 16);
}
__device__ __forceinline__ unsigned pk2(float a, float b) {
    return (unsigned)f2bf(a) | ((unsigned)f2bf(b) << 16);
}
__device__ __forceinline__ short8 u4s8(uint4 u) {
    union { uint4 a; short8 b; } cvt; cvt.a = u; return cvt.b;
}

// XCD-slab swizzle for 1152-block grids (k_fused)
__device__ __forceinline__ int swz1152(int bid) {
    return (bid & 7) * 144 + (bid >> 3);
}

// ---- init: pack w1/w2 into MFMA B-frag order (bf16) + zero gn accum + mm ----
__global__ __launch_bounds__(512) void k_init(const float* __restrict__ w1,
                                              const float* __restrict__ w2,
                                              unsigned* __restrict__ wf,
                                              float* __restrict__ gnacc,
                                              unsigned* __restrict__ mm) {
    int tid = threadIdx.x;
    if (blockIdx.x == 0) {
        if (tid < 256) gnacc[tid] = 0.f;
        if (tid < 2*BB) mm[tid] = (tid & 1) ? 0u : 0x7F800000u; // even=min(+inf bits), odd=max(0)
    }
    int i = blockIdx.x*512 + tid;             // grid 16 -> 8192
    if (i < 4096) {
        float2 v = ((const float2*)w1)[i];    // j = i>>5, c0 = (i&31)*2
        int j = i >> 5, cp = i & 31, c0 = cp << 1;
        int fi = ((j >> 4) << 1) + (c0 >> 5);
        int ln = (((c0 & 31) >> 3) << 4) + (j & 15);
        wf[fi*256 + ln*4 + (cp & 3)] = pk2(v.x, v.y);
    } else {
        int i2 = i - 4096;
        float2 v = ((const float2*)w2)[i2];   // c = i2>>6, j0 = (i2&63)*2
        int c = i2 >> 6, jp = i2 & 63, j0 = jp << 1;
        int fi = ((j0 >> 5) << 2) + (c >> 4);
        int ln = (((j0 & 31) >> 3) << 4) + (c & 15);
        wf[4096 + fi*256 + ln*4 + (jp & 3)] = pk2(v.x, v.y);
    }
}

// ---- row-based pre-pass: one block per (batch,row). LDS-staged input rows. ----
// Computes df, ||x||, 9 raw 3x3 dot products, GN partial sums, df min/max.
// Thread roles per block (256 threads): t<192 stage 1 float4/ch (rows->LDS);
// t<96 compute T[96] (bilinear column table); t in [96,192) own a pixel pair.
__global__ __launch_bounds__(256, 3) void k_pre(const float* __restrict__ x,
                                                float* __restrict__ df,
                                                float* __restrict__ nrm,
                                                float* __restrict__ dots,
                                                float* __restrict__ gnacc,
                                                unsigned* __restrict__ mm) {
    __shared__ __align__(16) float rb[2][4][WW];   // 6144 B, double-buffered 4 rows
    __shared__ float Tt[96];
    __shared__ float sgn[64];
    __shared__ float wred[8];

    int tid = threadIdx.x;
    int lane = tid & 63, wv = tid >> 6;
    if (tid < 64) sgn[tid] = 0.f;

    // XCD slab swizzle over 768 blocks (8 x 96)
    int virt = (blockIdx.x & 7) * 96 + (blockIdx.x >> 3);
    int b = virt / HH, h = virt % HH;

    // vertical mapping (identical formulas to the original per-pixel path)
    float hs = fminf(fmaxf(0.5f*(float)h - 0.25f, 0.f), 95.f);
    int hl = (int)hs; int hh2 = min(hl+1, 95); float fh = hs - (float)hl;
    int R[4] = {2*hl, 2*hl+1, 2*hh2, 2*hh2+1};
    // slots holding rows h-1, h, h+1 (missing -> 0, data masked by valid in k_fused)
    int su = 0, cs = 0, sd = 0;
    #pragma unroll
    for (int s = 3; s >= 0; --s) {
        if (R[s] == h-1) su = s;
        if (R[s] == h)   cs = s;
        if (R[s] == h+1) sd = s;
    }
    const float* xb = x + (size_t)b*CC*HWSZ;

    bool stager = tid < 192;
    int slot = (tid / 48) & 3, col4 = (tid % 48) * 4;
    const float* srow = xb + (size_t)R[slot]*WW + col4;

    bool isT  = tid < 96;
    bool ispx = (tid >= 96) && (tid < 192);
    int j  = tid - 96;                 // pixel pair index 0..95
    int w0 = 2*j, w1 = 2*j + 1;
    int cl = max(w0 - 1, 0), cr = min(w1 + 1, WW - 1);

    float dA[9], dB[9];
    #pragma unroll
    for (int k = 0; k < 9; ++k) { dA[k] = 0.f; dB[k] = 0.f; }
    float dfA = 0.f, dfB = 0.f, sAcc = 0.f, qAcc = 0.f;

    // prologue: stage channel 0, prefetch channel 1
    float4 v;
    if (stager) {
        v = *(const float4*)(srow);
        *(float4*)&rb[0][slot][col4] = v;
        v = *(const float4*)(srow + HWSZ);
    }
    __syncthreads();

    for (int c = 0; c < CC; ++c) {
        int cur = c & 1;
        // T table for this channel (reads rb[cur])
        if (isT) {
            float2 r0 = *(const float2*)&rb[cur][0][2*tid];
            float2 r1 = *(const float2*)&rb[cur][1][2*tid];
            float2 r2 = *(const float2*)&rb[cur][2][2*tid];
            float2 r3 = *(const float2*)&rb[cur][3][2*tid];
            float xdl = 0.25f*((r0.x + r1.x) + (r0.y + r1.y));
            float xdh = 0.25f*((r2.x + r3.x) + (r2.y + r3.y));
            Tt[tid] = (1.f - fh)*xdl + fh*xdh;
        }
        // stage next channel into the other buffer (written last iter's prefetch)
        if (stager && c+1 < CC) *(float4*)&rb[cur^1][slot][col4] = v;
        __syncthreads();
        // prefetch channel c+2 (consumed next iteration)
        if (stager && c+2 < CC) v = *(const float4*)(srow + (size_t)(c+2)*HWSZ);

        if (ispx) {
            float2 c01 = *(const float2*)&rb[cur][cs][w0];
            float xc0 = c01.x, xc1 = c01.y;
            // bilinear-upsampled value via T (exactly (1-fw)*T[wl] + fw*T[wh])
            float du0 = (j == 0)  ? Tt[0]  : 0.25f*Tt[j-1] + 0.75f*Tt[j];
            float du1 = (j == 95) ? Tt[95] : 0.75f*Tt[j]   + 0.25f*Tt[j+1];
            dfA += fabsf(xc0 - du0);
            dfB += fabsf(xc1 - du1);
            // 3x3 dot products (rows h-1,h,h+1)
            int rows[3] = {su, cs, sd};
            #pragma unroll
            for (int r = 0; r < 3; ++r) {
                int s = rows[r];
                float vl = rb[cur][s][cl];
                float2 v01 = *(const float2*)&rb[cur][s][w0];
                float vr = rb[cur][s][cr];
                dA[3*r+0] += xc0*vl;     dA[3*r+1] += xc0*v01.x;  dA[3*r+2] += xc0*v01.y;
                dB[3*r+0] += xc1*v01.x;  dB[3*r+1] += xc1*v01.y;  dB[3*r+2] += xc1*vr;
            }
            sAcc += xc0 + xc1;
            qAcc += xc0*xc0 + xc1*xc1;
        }
        // per channel-pair GN reduction (all threads; non-px hold zeros)
        if (c & 1) {
            float s_ = sAcc, q_ = qAcc;
            #pragma unroll
            for (int o = 1; o <= 32; o <<= 1) {
                s_ += __shfl_xor(s_, o);
                q_ += __shfl_xor(q_, o);
            }
            if (lane == 0) {
                atomicAdd(&sgn[c-1], s_);
                atomicAdd(&sgn[c],   q_);
            }
            sAcc = 0.f; qAcc = 0.f;
        }
        __syncthreads();
    }

    if (ispx) {
        size_t base = (size_t)b*HWSZ + h*WW + w0;
        *(float2*)&df[base]  = make_float2(dfA, dfB);
        *(float2*)&nrm[base] = make_float2(sqrtf(dA[4]), sqrtf(dB[4]));
        if (dots) {
            #pragma unroll
            for (int jj = 0; jj < 9; ++jj)
                *(float2*)&dots[(size_t)(b*9 + jj)*HWSZ + h*WW + w0] =
                    make_float2(dA[jj], dB[jj]);
        }
    }
    // block df min/max
    float mn = ispx ? fminf(dfA, dfB) : 3.4e38f;
    float mx = ispx ? fmaxf(dfA, dfB) : 0.f;
    #pragma unroll
    for (int o = 1; o <= 32; o <<= 1) {
        mn = fminf(mn, __shfl_xor(mn, o));
        mx = fmaxf(mx, __shfl_xor(mx, o));
    }
    if (lane == 0) { wred[wv] = mn; wred[4+wv] = mx; }
    __syncthreads();
    if (tid < 64) atomicAdd(&gnacc[(size_t)b*64 + tid], sgn[tid]);
    if (tid == 0) {
        float bmn = fminf(fminf(wred[0], wred[1]), fminf(wred[2], wred[3]));
        float bmx = fmaxf(fmaxf(wred[4], wred[5]), fmaxf(wred[6], wred[7]));
        atomicMin(&mm[2*b],   __float_as_uint(bmn));
        atomicMax(&mm[2*b+1], __float_as_uint(bmx));
    }
}

// ------- fused: softmax weights + GN affine (phase 1) + MFMA FFN (phase 2) -------
// USE_DOTS=1: 3x3 dot numerators precomputed by k_pre (9 coalesced loads).
// USE_DOTS=0: legacy in-kernel dot loop (small-workspace fallback).
template<int USE_DOTS>
__global__ __launch_bounds__(FTH, 4) void k_fused(const float* __restrict__ x,
                                                  const float* __restrict__ df,
                                                  const float* __restrict__ nrm,
                                                  const float* __restrict__ dots,
                                                  const unsigned* __restrict__ mm,
                                                  const float* __restrict__ gnacc,
                                                  const float* __restrict__ gw,
                                                  const float* __restrict__ gb,
                                                  const unsigned* __restrict__ wf,
                                                  const float* __restrict__ b1,
                                                  const float* __restrict__ b2,
                                                  float* __restrict__ out) {
    __shared__ __align__(16) unsigned char lds[24576];
    unsigned* se = (unsigned*)lds;                  // 4096 uints
    unsigned* sh = (unsigned*)(lds + 16384);        // 2048 uints
    float* gnv = (float*)(lds + 16384);             // [32 groups][mu, rsigma]

    int tid = threadIdx.x;
    int wv = tid >> 6, lane = tid & 63;
    int q = lane >> 4, m = lane & 15;               // quarter (ch group), pixel row

    int virt = swz1152(blockIdx.x);
    int b = virt / FBPB;
    int pb = (virt % FBPB) * FPX;
    int pxl = wv*16 + m;                            // 0..127 local pixel
    int p = pb + pxl;
    int h = p / WW, w = p % WW;
    int cbase = q*16;

    // finalize GN stats in-block
    if (tid < 32) {
        float n = 2.f*HWSZ;
        float mu  = gnacc[(size_t)b*64 + 2*tid] / n;
        float var = gnacc[(size_t)b*64 + 2*tid + 1] / n - mu*mu;
        gnv[2*tid]   = mu;
        gnv[2*tid+1] = rsqrtf(var + 1e-5f);
    }
    __syncthreads();

    // ================= phase 1 =================
    float dmin = __uint_as_float(mm[2*b]);
    float dmax = __uint_as_float(mm[2*b+1]);
    float dfp = (df[b*HWSZ+p] - dmin) / (dmax - dmin + 1e-8f);
    dfp = dfp * dfp;
    bool maskv = dfp > 0.3f;
    float conn = 1.f + (maskv ? fmaxf(rintf(dfp * 15.f), 0.f) : 0.f);
    bool process = conn > 1.f;
    int kk = (int)fminf(conn, 9.f);

    const float* xb = x + (size_t)b*CC*HWSZ + p;
    const int dhv[9] = {-1,-1,-1, 0,0,0, 1,1,1};
    const int dwv[9] = {-1, 0, 1,-1,0,1,-1,0,1};
    bool valid[9]; int offc[9];
    #pragma unroll
    for (int jj = 0; jj < 9; ++jj) {
        int hn = h + dhv[jj], wn = w + dwv[jj];
        valid[jj] = (hn >= 0) && (hn < HH) && (wn >= 0) && (wn < WW);
        offc[jj] = valid[jj] ? (dhv[jj]*WW + dwv[jj]) : 0;
    }
    float wtc[9];
    #pragma unroll
    for (int jj = 0; jj < 9; ++jj) wtc[jj] = 0.f;

    if (process) {
        float dot[9];
        if (USE_DOTS) {
            const float* dp = dots + (size_t)b*9*HWSZ + p;
            #pragma unroll
            for (int jj = 0; jj < 9; ++jj)
                dot[jj] = dp[(size_t)jj*HWSZ];
        } else {
            #pragma unroll
            for (int jj = 0; jj < 9; ++jj) dot[jj] = 0.f;
            #pragma unroll 2
            for (int cc = 0; cc < 16; ++cc) {
                const float* pc = xb + (size_t)(cbase + cc)*HWSZ;
                float xc = pc[0];
                #pragma unroll
                for (int jj = 0; jj < 9; ++jj)
                    dot[jj] += xc * pc[offc[jj]];
            }
            #pragma unroll
            for (int jj = 0; jj < 9; ++jj) {
                dot[jj] += __shfl_xor(dot[jj], 16);
                dot[jj] += __shfl_xor(dot[jj], 32);
            }
        }
        float nc = fmaxf(nrm[b*HWSZ+p], 1e-12f);
        float sim[9];
        #pragma unroll
        for (int jj = 0; jj < 9; ++jj) {
            float nj = fmaxf(nrm[b*HWSZ+p+offc[jj]], 1e-12f);
            sim[jj] = valid[jj] ? dot[jj] / (nc * nj) : 0.f;
        }
        float S = 0.f;
        float wt[9];
        #pragma unroll
        for (int jj = 0; jj < 9; ++jj) {
            int rank = 0;
            #pragma unroll
            for (int l = 0; l < 9; ++l)
                rank += (sim[l] > sim[jj]) || (sim[l] == sim[jj] && l < jj);
            float ex = (rank < kk) ? expf(sim[jj]) : 0.f;  // stable argsort(-sim) top-k
            wt[jj] = ex; S += ex;
        }
        float inv = 1.f / fmaxf(S, 1e-12f);
        #pragma unroll
        for (int jj = 0; jj < 9; ++jj)
            wtc[jj] = valid[jj] ? wt[jj] * inv : 0.f;
    }

    float e[16];
    for (int cc = 0; cc < 16; ++cc) {
        int c = cbase + cc;
        const float* pc = xb + (size_t)c*HWSZ;
        float xc = pc[0];
        float oc;
        if (process) {
            float a = 0.f;
            #pragma unroll
            for (int jj = 0; jj < 9; ++jj)
                a += wtc[jj] * pc[offc[jj]];
            oc = a;
        } else oc = xc;
        int g = c >> 1;
        float mu = gnv[2*g], is = gnv[2*g+1];
        e[cc] = oc + (xc - mu) * is * gw[c] + gb[c];
    }

    // e -> A-frag order: tile wv, kc=q>>1, k = 16*(q&1)+j
    {
        int kc = q >> 1, qo = q & 1;
        unsigned* dst = se + (wv*2 + kc)*256;
        int la = 32*qo + m;
        uint4 ua, ub;
        ua.x = pk2(e[0],e[1]);  ua.y = pk2(e[2],e[3]);
        ua.z = pk2(e[4],e[5]);  ua.w = pk2(e[6],e[7]);
        ub.x = pk2(e[8],e[9]);  ub.y = pk2(e[10],e[11]);
        ub.z = pk2(e[12],e[13]); ub.w = pk2(e[14],e[15]);
        *(uint4*)(dst + la*4)      = ua;
        *(uint4*)(dst + (la+16)*4) = ub;
    }
    __syncthreads();

    // ================= phase 2: MFMA FFN (tile = wv, 16 px) =================
    const unsigned* wf1g = wf;
    const unsigned* wf2g = wf + 4096;
    int n16 = m;
    float b1v[8], b2v[4];
    #pragma unroll
    for (int nt = 0; nt < 8; ++nt) b1v[nt] = b1[nt*16 + n16];
    #pragma unroll
    for (int n2 = 0; n2 < 4; ++n2) b2v[n2] = b2[n2*16 + n16];

    uint4 a0 = *(uint4*)(se + (wv*2+0)*256 + lane*4);
    uint4 a1 = *(uint4*)(se + (wv*2+1)*256 + lane*4);
    f32x4 D1[8];
    #pragma unroll
    for (int nt = 0; nt < 8; ++nt) D1[nt] = (f32x4){0.f,0.f,0.f,0.f};
    #pragma unroll
    for (int nt = 0; nt < 8; ++nt) {
        uint4 bk0 = *(const uint4*)(wf1g + (nt*2+0)*256 + lane*4);
        uint4 bk1 = *(const uint4*)(wf1g + (nt*2+1)*256 + lane*4);
        D1[nt] = __builtin_amdgcn_mfma_f32_16x16x32_bf16(u4s8(a0), u4s8(bk0), D1[nt], 0, 0, 0);
        D1[nt] = __builtin_amdgcn_mfma_f32_16x16x32_bf16(u4s8(a1), u4s8(bk1), D1[nt], 0, 0, 0);
    }
    f32x4 D2[4];
    #pragma unroll
    for (int n2 = 0; n2 < 4; ++n2) D2[n2] = (f32x4){0.f,0.f,0.f,0.f};
    unsigned* shwv = sh + wv*256;
    unsigned short* shw = (unsigned short*)shwv;
    for (int kc2 = 0; kc2 < 4; ++kc2) {
        #pragma unroll
        for (int h2 = 0; h2 < 2; ++h2) {
            int nt = kc2*2 + h2;
            #pragma unroll
            for (int r = 0; r < 4; ++r) {
                float hval = fmaxf(D1[nt][r] + b1v[nt], 0.f);
                int mrow = q*4 + r;
                int k = h2*16 + n16;
                shw[((k >> 3)*16 + mrow)*8 + (k & 7)] = f2bf(hval);
            }
        }
        uint4 ah = *(uint4*)(shwv + lane*4);        // same-wave LDS RAW: in-order
        #pragma unroll
        for (int n2 = 0; n2 < 4; ++n2) {
            uint4 bb = *(const uint4*)(wf2g + (kc2*4 + n2)*256 + lane*4);
            D2[n2] = __builtin_amdgcn_mfma_f32_16x16x32_bf16(u4s8(ah), u4s8(bb), D2[n2], 0, 0, 0);
        }
    }
    // residual + b2 into regs
    float vals[4][4];
    unsigned short* seu = (unsigned short*)se;
    #pragma unroll
    for (int n2 = 0; n2 < 4; ++n2) {
        int c = n2*16 + n16;
        int kc = c >> 5, qq = (c & 31) >> 3, jj = c & 7;
        #pragma unroll
        for (int r = 0; r < 4; ++r) {
            int pxt = q*4 + r;
            float resid = bf2f(seu[((wv*2+kc)*64 + qq*16 + pxt)*8 + jj]);
            vals[n2][r] = D2[n2][r] + resid + b2v[n2];
        }
    }
    __syncthreads();                                 // se dead; reuse as staging

    // ---- coalesced epilogue: 2 rounds of 32 channels via fp32 staging ----
    float* stg = (float*)lds;                        // [32 rows][stride 132]
    float* outb = out + (size_t)b*CC*HWSZ;
    #pragma unroll
    for (int g = 0; g < 2; ++g) {
        #pragma unroll
        for (int hn2 = 0; hn2 < 2; ++hn2) {
            int n2 = 2*g + hn2;
            int row = (n2 & 1)*16 + n16;
            float4 v4 = make_float4(vals[n2][0], vals[n2][1], vals[n2][2], vals[n2][3]);
            *(float4*)&stg[row*132 + wv*16 + q*4] = v4;
        }
        __syncthreads();
        #pragma unroll
        for (int rr = 0; rr < 2; ++rr) {
            int r0 = (wv*2 + rr)*2 + (lane >> 5);    // 0..31
            int px4 = (lane & 31) * 4;
            float4 vv = *(float4*)&stg[r0*132 + px4];
            *(float4*)&outb[(size_t)(g*32 + r0)*HWSZ + pb + px4] = vv;
        }
        if (g == 0) __syncthreads();
    }
}

extern "C" void kernel_launch(void* const* d_in, const int* in_sizes, int n_in,
                              void* d_out, int out_size, void* d_ws, size_t ws_size,
                              hipStream_t stream) {
    const float* x  = (const float*)d_in[0];
    const float* gw = (const float*)d_in[1];
    const float* gb = (const float*)d_in[2];
    const float* w1 = (const float*)d_in[3];
    const float* b1 = (const float*)d_in[4];
    const float* w2 = (const float*)d_in[5];
    const float* b2 = (const float*)d_in[6];
    float* out = (float*)d_out;

    // ws layout: df | nrm | gnacc | mm | wf | dots
    float* df    = (float*)d_ws;
    float* nrm   = df + 147456;
    float* gnacc = nrm + 147456;
    unsigned* mm = (unsigned*)(gnacc + 256);
    unsigned* wf = mm + 8;
    float* dots  = (float*)(wf + 8192);
    const size_t NEED = (size_t)(147456*2 + 256 + 8 + 8192 + 9*147456) * 4;
    bool big = ws_size >= NEED;
    float* dotsArg = big ? dots : nullptr;

    k_init<<<16, 512, 0, stream>>>(w1, w2, wf, gnacc, mm);
    k_pre <<<BB*HH, 256, 0, stream>>>(x, df, nrm, dotsArg, gnacc, mm);
    if (big)
        k_fused<1><<<BB*FBPB, FTH, 0, stream>>>(x, df, nrm, dots, mm, gnacc,
                                                gw, gb, wf, b1, b2, out);
    else
        k_fused<0><<<BB*FBPB, FTH, 0, stream>>>(x, df, nrm, nullptr, mm, gnacc,
                                                gw, gb, wf, b1, b2, out);
}